// Round 3
// baseline (144.021 us; speedup 1.0000x reference)
//
#include <hip/hip_runtime.h>

#define HWC 4096
#define WC 64
#define HC 64
#define DC 256
#define BC 2
#define KKC 81

// ---------------- transpose [B, D, HW] -> [B, HW, D] ----------------
__global__ __launch_bounds__(256) void transpose_k(const float* __restrict__ in,
                                                   float* __restrict__ out) {
    __shared__ float tile[32][33];
    const int m0 = blockIdx.x * 32, d0 = blockIdx.y * 32, b = blockIdx.z;
    const int tx = threadIdx.x, ty = threadIdx.y;
    const size_t ib = (size_t)b * DC * HWC;
#pragma unroll
    for (int k = 0; k < 4; ++k) {
        int d = d0 + ty + k * 8;
        tile[ty + k * 8][tx] = in[ib + (size_t)d * HWC + m0 + tx];
    }
    __syncthreads();
#pragma unroll
    for (int k = 0; k < 4; ++k) {
        int m = m0 + ty + k * 8;
        out[ib + (size_t)m * DC + d0 + tx] = tile[tx][ty + k * 8];
    }
}

// ---------------- fused neighborhood-corr + bilinear ----------------
// One block per output pixel (b, hw). 4 waves x 25 grid dots = 100 dots over
// the 10x10 integer grid; then 81 bilinear combines with scalar weights.
// Reference quirk (RAFT): out[n, i, j] samples at x = x_c + (i-4), y = y_c + (j-4)
// -> FIRST K index walks x, SECOND walks y.
template <bool TRANS>
__global__ __launch_bounds__(256) void corr_k(const float* __restrict__ f1,
                                              const float* __restrict__ f2,
                                              const float* __restrict__ coords,
                                              float* __restrict__ out) {
    __shared__ float Cs[100];  // Cs[yi*10+xi] = corr(y = iy0-4+yi, x = ix0-4+xi)

    const int bid = blockIdx.x;
    // XCD swizzle: batch 0 -> XCDs 0..3, batch 1 -> XCDs 4..7 (perf heuristic only)
    const int xcd = bid & 7;
    const int b = xcd >> 2;
    const int hw = ((bid >> 3) << 2) + (xcd & 3);

    const int tid = threadIdx.x;
    const int lane = tid & 63;
    const int wv = tid >> 6;

    const float x = coords[((size_t)b * 2 + 0) * HWC + hw];
    const float y = coords[((size_t)b * 2 + 1) * HWC + hw];
    const float x0f = floorf(x), y0f = floorf(y);
    const float wx = x - x0f, wy = y - y0f;
    const int ix0 = (int)x0f, iy0 = (int)y0f;

    // f1 feature fragment for this lane (4 consecutive d), scaled by 1/sqrt(D)=1/16
    float4 a;
    if (TRANS) {
        a = *(const float4*)(f1 + ((size_t)b * HWC + hw) * DC + lane * 4);
    } else {
        const float* base = f1 + (size_t)b * DC * HWC + hw;
        a.x = base[(size_t)(lane * 4 + 0) * HWC];
        a.y = base[(size_t)(lane * 4 + 1) * HWC];
        a.z = base[(size_t)(lane * 4 + 2) * HWC];
        a.w = base[(size_t)(lane * 4 + 3) * HWC];
    }
    a.x *= 0.0625f; a.y *= 0.0625f; a.z *= 0.0625f; a.w *= 0.0625f;

    // 100 grid dots, 25 per wave; gy/gx wave-uniform so the valid branch is uniform
    for (int t = wv * 25; t < wv * 25 + 25; ++t) {
        const int yi = t / 10, xi = t % 10;
        const int gy = iy0 - 4 + yi, gx = ix0 - 4 + xi;
        float s = 0.f;
        if (gx >= 0 && gx < WC && gy >= 0 && gy < HC) {
            float4 v;
            if (TRANS) {
                v = *(const float4*)(f2 + ((size_t)b * HWC + gy * WC + gx) * DC + lane * 4);
            } else {
                const float* base = f2 + (size_t)b * DC * HWC + gy * WC + gx;
                v.x = base[(size_t)(lane * 4 + 0) * HWC];
                v.y = base[(size_t)(lane * 4 + 1) * HWC];
                v.z = base[(size_t)(lane * 4 + 2) * HWC];
                v.w = base[(size_t)(lane * 4 + 3) * HWC];
            }
            s = a.x * v.x + a.y * v.y + a.z * v.z + a.w * v.w;
        }
        // wave64 butterfly reduce
#pragma unroll
        for (int m = 32; m >= 1; m >>= 1) s += __shfl_xor(s, m, 64);
        if (lane == 0) Cs[t] = s;
    }
    __syncthreads();

    if (tid < KKC) {
        const int i = tid / 9, j = tid % 9;  // i walks x, j walks y (RAFT quirk)
        const float w00 = (1.f - wx) * (1.f - wy);
        const float w01 = wx * (1.f - wy);
        const float w10 = (1.f - wx) * wy;
        const float w11 = wx * wy;
        const float r = w00 * Cs[j * 10 + i]       + w01 * Cs[j * 10 + i + 1] +
                        w10 * Cs[(j + 1) * 10 + i] + w11 * Cs[(j + 1) * 10 + i + 1];
        out[((size_t)(b * KKC + tid)) * HWC + hw] = r;
    }
}

extern "C" void kernel_launch(void* const* d_in, const int* in_sizes, int n_in,
                              void* d_out, int out_size, void* d_ws, size_t ws_size,
                              hipStream_t stream) {
    const float* fmap1 = (const float*)d_in[0];
    const float* fmap2 = (const float*)d_in[1];
    const float* coords = (const float*)d_in[2];
    float* out = (float*)d_out;

    const size_t per = (size_t)BC * HWC * DC;          // elements per transposed map
    const size_t needed = 2 * per * sizeof(float);     // 16 MB

    if (ws_size >= needed) {
        float* f1t = (float*)d_ws;
        float* f2t = f1t + per;
        transpose_k<<<dim3(128, 8, 2), dim3(32, 8), 0, stream>>>(fmap1, f1t);
        transpose_k<<<dim3(128, 8, 2), dim3(32, 8), 0, stream>>>(fmap2, f2t);
        corr_k<true><<<dim3(8192), dim3(256), 0, stream>>>(f1t, f2t, coords, out);
    } else {
        corr_k<false><<<dim3(8192), dim3(256), 0, stream>>>(fmap1, fmap2, coords, out);
    }
}

// Round 4
// 91.748 us; speedup vs baseline: 1.5698x; 1.5698x over previous
//
#include <hip/hip_runtime.h>

#define HWC 4096
#define WC 64
#define HC 64
#define DC 256
#define BC 2
#define KKC 81

typedef _Float16 h2 __attribute__((ext_vector_type(2)));
typedef _Float16 h8 __attribute__((ext_vector_type(8)));

static __device__ inline float dot8(h8 v, h8 a, float s) {
#if __has_builtin(__builtin_amdgcn_fdot2)
    s = __builtin_amdgcn_fdot2((h2){v[0], v[1]}, (h2){a[0], a[1]}, s, false);
    s = __builtin_amdgcn_fdot2((h2){v[2], v[3]}, (h2){a[2], a[3]}, s, false);
    s = __builtin_amdgcn_fdot2((h2){v[4], v[5]}, (h2){a[4], a[5]}, s, false);
    s = __builtin_amdgcn_fdot2((h2){v[6], v[7]}, (h2){a[6], a[7]}, s, false);
#else
#pragma unroll
    for (int k = 0; k < 8; ++k) s += (float)v[k] * (float)a[k];
#endif
    return s;
}

// ------- fused transpose+cast: [B, D, HW] f32 -> [B, HW, D] f16, both maps -------
__global__ __launch_bounds__(256) void transpose_h_k(const float* __restrict__ f1,
                                                     const float* __restrict__ f2,
                                                     _Float16* __restrict__ o1,
                                                     _Float16* __restrict__ o2) {
    __shared__ float tile[64][33];
    const int z = blockIdx.z;              // z = map*2 + b
    const int b = z & 1;
    const float* in = (z >> 1) ? f2 : f1;
    _Float16* out = (z >> 1) ? o2 : o1;
    in += (size_t)b * DC * HWC;
    out += (size_t)b * HWC * DC;

    const int m0 = blockIdx.x * 32, d0 = blockIdx.y * 64;
    const int tx = threadIdx.x, ty = threadIdx.y;  // (32, 8)
#pragma unroll
    for (int k = 0; k < 8; ++k) {
        const int d = d0 + ty + k * 8;
        tile[ty + k * 8][tx] = in[(size_t)d * HWC + m0 + tx];
    }
    __syncthreads();
#pragma unroll
    for (int k = 0; k < 4; ++k) {
        const int ml = ty + k * 8;
        const int m = m0 + ml;
        h2 h = {(_Float16)tile[2 * tx][ml], (_Float16)tile[2 * tx + 1][ml]};
        ((h2*)(out + (size_t)m * DC + d0))[tx] = h;
    }
}

// ---------------- fused neighborhood-corr + bilinear ----------------
// One block per output pixel (b, hw). 16 groups of 16 lanes; each group owns one
// grid dot per iteration (100 dots over the 10x10 integer patch), lane holds 16
// consecutive d-elements -> 4-step shuffle reduce. Then 81 bilinear combines.
// Reference quirk (RAFT): out[n, i, j] samples at x = x_c + (i-4), y = y_c + (j-4).
__global__ __launch_bounds__(256) void corr_k(const _Float16* __restrict__ f1t,
                                              const _Float16* __restrict__ f2t,
                                              const float* __restrict__ coords,
                                              float* __restrict__ out) {
    __shared__ float Cs[100];  // Cs[yi*10+xi] = corr(y = iy0-4+yi, x = ix0-4+xi)

    const int bid = blockIdx.x;
    // XCD swizzle: batch 0 -> XCDs 0..3, batch 1 -> XCDs 4..7 (each batch's 4MB
    // f16 f2t fits the XCD group's L2)
    const int xcd = bid & 7;
    const int b = xcd >> 2;
    const int hw = ((bid >> 3) << 2) + (xcd & 3);

    const int tid = threadIdx.x;
    const int g = tid >> 4;    // group 0..15
    const int l = tid & 15;    // lane-in-group

    const float x = coords[((size_t)b * 2 + 0) * HWC + hw];
    const float y = coords[((size_t)b * 2 + 1) * HWC + hw];
    const float x0f = floorf(x), y0f = floorf(y);
    const float wx = x - x0f, wy = y - y0f;
    const int ix0 = (int)x0f, iy0 = (int)y0f;

    // f1 fragment: 16 consecutive d for this lane (shared across groups via cache)
    const h8* ap = (const h8*)(f1t) + ((size_t)(b * HWC + hw)) * 32 + l * 2;
    const h8 a0 = ap[0], a1 = ap[1];
    const h8* f2b = (const h8*)(f2t) + (size_t)b * HWC * 32;

#pragma unroll
    for (int it = 0; it < 7; ++it) {
        const int t = it * 16 + g;
        if (t < 100) {
            const int yi = t / 10, xi = t - yi * 10;
            const int gy = iy0 - 4 + yi, gx = ix0 - 4 + xi;
            float s = 0.f;
            if (gx >= 0 && gx < WC && gy >= 0 && gy < HC) {
                const h8* vp = f2b + (size_t)(gy * WC + gx) * 32 + l * 2;
                const h8 v0 = vp[0], v1 = vp[1];
                s = dot8(v0, a0, s);
                s = dot8(v1, a1, s);
            }
            // 16-lane group reduce
            s += __shfl_xor(s, 1, 64);
            s += __shfl_xor(s, 2, 64);
            s += __shfl_xor(s, 4, 64);
            s += __shfl_xor(s, 8, 64);
            if (l == 0) Cs[t] = s * 0.0625f;  // 1/sqrt(256)
        }
    }
    __syncthreads();

    if (tid < KKC) {
        const int i = tid / 9, j = tid % 9;  // i walks x, j walks y (RAFT quirk)
        const float w00 = (1.f - wx) * (1.f - wy);
        const float w01 = wx * (1.f - wy);
        const float w10 = (1.f - wx) * wy;
        const float w11 = wx * wy;
        const float r = w00 * Cs[j * 10 + i]       + w01 * Cs[j * 10 + i + 1] +
                        w10 * Cs[(j + 1) * 10 + i] + w11 * Cs[(j + 1) * 10 + i + 1];
        out[((size_t)(b * KKC + tid)) * HWC + hw] = r;
    }
}

extern "C" void kernel_launch(void* const* d_in, const int* in_sizes, int n_in,
                              void* d_out, int out_size, void* d_ws, size_t ws_size,
                              hipStream_t stream) {
    const float* fmap1 = (const float*)d_in[0];
    const float* fmap2 = (const float*)d_in[1];
    const float* coords = (const float*)d_in[2];
    float* out = (float*)d_out;

    const size_t perH = (size_t)BC * HWC * DC;  // f16 elements per transposed map
    _Float16* f1t = (_Float16*)d_ws;
    _Float16* f2t = f1t + perH;

    transpose_h_k<<<dim3(HWC / 32, DC / 64, 4), dim3(32, 8), 0, stream>>>(fmap1, fmap2, f1t, f2t);
    corr_k<<<dim3(BC * HWC), dim3(256), 0, stream>>>(f1t, f2t, coords, out);
}